// Round 8
// baseline (39.196 us; speedup 1.0000x reference)
//
#include <hip/hip_runtime.h>
#include <hip/hip_bf16.h>

// Problem constants
#define N_SAMP 256
#define C_IN 2
#define T_FRAMES 120
#define V_JOINTS 13
#define LEN_KEEP 72          // int(120 * 0.6)
#define N_MASK_J 6           // int(13 * 0.5)
#define N_KEEP_J 7
#define H_DIM 64
#define E_DIM 256
#define POS_PER_SAMPLE (T_FRAMES * V_JOINTS)   // 1560
#define NPOS (LEN_KEEP * N_KEEP_J)             // 504 real positions
#define NROW 512                               // padded rows (16-multiple)
#define NPT (NROW / 16)                        // 32 position tiles
#define THREADS 512

typedef __attribute__((ext_vector_type(8))) __bf16 bf16x8;
typedef __attribute__((ext_vector_type(4))) float f32x4;

// ---------------------------------------------------------------------------
// Kernel 1 (prep): blocks [0,13)   : dpeproj = w_dec . dec_pos_embed
//                  blocks [13,77)  : w_enc fp32 -> bf16
//                  blocks [77,333) : per-sample masking indices -> srcg/revg
// ---------------------------------------------------------------------------
__global__ __launch_bounds__(256)
void prep_kernel(const float* __restrict__ w_dec,         // (2,256)
                 const float* __restrict__ dec_pos_embed, // (1,256,120,13)
                 const float* __restrict__ w_enc,         // (256,64)
                 const float* __restrict__ frame_noise,   // (256,120)
                 const float* __restrict__ joint_noise,   // (256,72,13)
                 float* __restrict__ dpeproj,             // (2,1560)
                 __bf16* __restrict__ wbf,                // (256,64)
                 int* __restrict__ srcg,                  // (256,504) gather src
                 short* __restrict__ revg)                // (256,1560) -1 or slot
{
    int bid = blockIdx.x;
    int tid = threadIdx.x;

    if (bid < 13) {
        int i = bid * 256 + tid;
        if (i < C_IN * POS_PER_SAMPLE) {
            int o = i / POS_PER_SAMPLE;
            int p = i - o * POS_PER_SAMPLE;
            float s = 0.f;
            #pragma unroll 4
            for (int c = 0; c < E_DIM; ++c)
                s += w_dec[o * E_DIM + c] * dec_pos_embed[c * POS_PER_SAMPLE + p];
            dpeproj[i] = s;
        }
        return;
    }
    if (bid < 77) {
        int i = (bid - 13) * 256 + tid;
        if (i < E_DIM * H_DIM) wbf[i] = (__bf16)w_enc[i];
        return;
    }

    // ---- per-sample index computation ----
    int n = bid - 77;
    __shared__ float noise_sh[T_FRAMES];
    __shared__ int rank_sh[T_FRAMES];
    __shared__ int ids_keep_sh[LEN_KEEP];
    __shared__ int tout_sh[LEN_KEEP];
    __shared__ short rev_sh[POS_PER_SAMPLE];

    if (tid < T_FRAMES) noise_sh[tid] = frame_noise[n * T_FRAMES + tid];
    for (int i = tid; i < POS_PER_SAMPLE; i += 256) rev_sh[i] = -1;
    __syncthreads();

    if (tid < T_FRAMES) {
        float v = noise_sh[tid];
        int r = 0;
        #pragma unroll 4
        for (int j = 0; j < T_FRAMES; ++j) {
            float u = noise_sh[j];
            r += (u < v || (u == v && j < tid)) ? 1 : 0;   // stable argsort rank
        }
        rank_sh[tid] = r;
    }
    __syncthreads();

    if (tid < T_FRAMES) {
        int kc = 0;                                  // #kept frames with index < tid
        #pragma unroll 4
        for (int j = 0; j < tid; ++j) kc += (rank_sh[j] < LEN_KEEP) ? 1 : 0;
        if (rank_sh[tid] < LEN_KEEP) ids_keep_sh[kc] = tid;
        // tout_sh[v]: output frame t where frame_ids[t] == v (v < 72)
        if (tid < LEN_KEEP)
            tout_sh[tid] = (rank_sh[tid] < LEN_KEEP) ? kc : LEN_KEEP + (tid - kc);
    }
    __syncthreads();

    if (tid < LEN_KEEP) {
        int f = tid;
        const float* jn = joint_noise + (n * LEN_KEEP + f) * V_JOINTS;
        float jv[V_JOINTS];
        for (int v = 0; v < V_JOINTS; ++v) jv[v] = jn[v];
        int jrank[V_JOINTS];
        for (int v = 0; v < V_JOINTS; ++v) {
            int r = 0;
            for (int u = 0; u < V_JOINTS; ++u)
                r += (jv[u] < jv[v] || (jv[u] == jv[v] && u < v)) ? 1 : 0;
            jrank[v] = r;
        }
        int comb[V_JOINTS];
        int idx = 0;
        for (int v = 0; v < V_JOINTS; ++v) if (jrank[v] >= N_MASK_J) comb[idx++] = v;
        for (int v = 0; v < V_JOINTS; ++v) if (jrank[v] <  N_MASK_J) comb[idx++] = v;
        int vout[N_KEEP_J];
        for (int v = 0; v < V_JOINTS; ++v) {
            int s = comb[v];
            if (s < N_KEEP_J) vout[s] = v;
        }
        int tsrc = ids_keep_sh[f];
        int tout = tout_sh[f];
        for (int s = 0; s < N_KEEP_J; ++s) {
            int p = f * N_KEEP_J + s;
            srcg[n * NPOS + p] = tsrc * V_JOINTS + comb[s];
            rev_sh[tout * V_JOINTS + vout[s]] = (short)p;
        }
    }
    __syncthreads();

    for (int i = tid; i < POS_PER_SAMPLE; i += 256)
        revg[n * POS_PER_SAMPLE + i] = rev_sh[i];
}

// ---------------------------------------------------------------------------
// Kernel 2: fused per-sample kernel. 256 blocks x 512 threads, 3 barriers.
//   phase A/B: load src/rev tables + gather x + pos_embed (504 positions)
//   phase C:   h = leaky(W_in x + b) -> bf16 LDS [512][64], XOR-swizzled
//   phase D:   MFMA 64->256 e-stage + fused 256->2 decoder, waves split
//              (ctg: 4 channel-tiles) x (ptg: 16 position-tiles)
//   phase E:   out[n] = dpeproj + sum_ctg pdpart via rev map
// ---------------------------------------------------------------------------
__global__ __launch_bounds__(THREADS, 1)
void fused_kernel(const float* __restrict__ x,            // (256,2,120,13)
                  const float* __restrict__ pos_embed,    // (1,2,120,13)
                  const float* __restrict__ w_in,         // (64,2)
                  const float* __restrict__ b_in,         // (64,)
                  const __bf16* __restrict__ wbf,         // (256,64) bf16
                  const float* __restrict__ w_dec,        // (2,256)
                  const float* __restrict__ dpeproj,      // (2,1560)
                  const int* __restrict__ srcg,           // (256,504)
                  const short* __restrict__ revg,         // (256,1560)
                  float* __restrict__ out)                // (256,2,120,13)
{
    __shared__ __align__(16) char h_raw[NROW * 128];   // 64 KB bf16 [512][64]
    __shared__ float2 xm_sh[NROW];
    __shared__ short rev_sh[POS_PER_SAMPLE];           // -1 or position index
    __shared__ float pdpart[4][NPOS][2];               // per-ctg decoder partials

    int n = blockIdx.x;
    int tid = threadIdx.x;
    int lane = tid & 63, wave = tid >> 6;
    int g = lane >> 4;       // k-group / D-row-group
    int r16 = lane & 15;     // A-row (channel) / B-col (position)
    int ctg = wave & 3;      // this wave's 4 channel-tiles: ct = ctg*4+i
    int ptg = wave >> 2;     // this wave's 16 position-tiles

    // ---- hoisted loads: w_enc A-fragments (8) + w_dec rows (8) per wave ----
    bf16x8 wfr[4][2];
    f32x4 wd0r[4], wd1r[4];
    {
        const bf16x8* wq = (const bf16x8*)wbf;
        #pragma unroll
        for (int i = 0; i < 4; ++i) {
            int ct = ctg * 4 + i;
            wfr[i][0] = wq[(ct * 16 + r16) * 8 + 0 + g];
            wfr[i][1] = wq[(ct * 16 + r16) * 8 + 4 + g];
            wd0r[i] = *(const f32x4*)(w_dec + ct * 16 + g * 4);
            wd1r[i] = *(const f32x4*)(w_dec + E_DIM + ct * 16 + g * 4);
        }
    }

    // ---- phase A/B: load tables + gather x + pos_embed ----
    if (tid < NROW) {
        if (tid < NPOS) {
            int so = srcg[n * NPOS + tid];
            float x0 = x[(n * 2 + 0) * POS_PER_SAMPLE + so] + pos_embed[so];
            float x1 = x[(n * 2 + 1) * POS_PER_SAMPLE + so] + pos_embed[POS_PER_SAMPLE + so];
            xm_sh[tid] = make_float2(x0, x1);
        } else {
            xm_sh[tid] = make_float2(0.f, 0.f);
        }
    }
    for (int i = tid; i < POS_PER_SAMPLE; i += THREADS)
        rev_sh[i] = revg[n * POS_PER_SAMPLE + i];
    __syncthreads();

    // ---- phase C: h[p][k] = leaky(w_in[k,:].xm[p] + b[k]) -> bf16 LDS ----
    {
        int kq = lane;
        float wi0 = w_in[kq * 2 + 0], wi1 = w_in[kq * 2 + 1], bk = b_in[kq];
        for (int p = wave; p < NROW; p += 8) {
            float2 xm = xm_sh[p];
            float hv = fmaf(wi0, xm.x, fmaf(wi1, xm.y, bk));
            hv = fmaxf(hv, 0.1f * hv);                    // leaky
            int off = (p * 128 + kq * 2) ^ ((p & 7) << 4);
            *(__bf16*)(h_raw + off) = (__bf16)hv;
        }
    }
    __syncthreads();

    // ---- phase D: MFMA e-stage + fused decoder ----
    // wave (ctg,ptg): channels [ctg*64, ctg*64+64), tiles [ptg*16, ptg*16+16)
    for (int t = 0; t < 16; ++t) {
        int pt = ptg * 16 + t;
        int row = pt * 16 + r16;
        int swz = (row & 7) << 4;
        bf16x8 b0 = *(const bf16x8*)(h_raw + ((row * 128 + g * 16) ^ swz));
        bf16x8 b1 = *(const bf16x8*)(h_raw + ((row * 128 + 64 + g * 16) ^ swz));

        float pd0 = 0.f, pd1 = 0.f;
        #pragma unroll
        for (int i = 0; i < 4; ++i) {
            f32x4 acc = {0.f, 0.f, 0.f, 0.f};
            acc = __builtin_amdgcn_mfma_f32_16x16x32_bf16(wfr[i][0], b0, acc, 0, 0, 0);
            acc = __builtin_amdgcn_mfma_f32_16x16x32_bf16(wfr[i][1], b1, acc, 0, 0, 0);
            // D layout: channel c = (ctg*4+i)*16 + g*4 + r, position p = pt*16 + r16
            #pragma unroll
            for (int r = 0; r < 4; ++r) {
                float e = acc[r];
                e = fmaxf(e, 0.1f * e);                   // leaky
                pd0 = fmaf(wd0r[i][r], e, pd0);
                pd1 = fmaf(wd1r[i][r], e, pd1);
            }
        }
        // reduce over the 4 g-groups (lane bits 4,5)
        pd0 += __shfl_xor(pd0, 16); pd0 += __shfl_xor(pd0, 32);
        pd1 += __shfl_xor(pd1, 16); pd1 += __shfl_xor(pd1, 32);

        int p = pt * 16 + r16;
        if (lane < 16 && p < NPOS) {
            pdpart[ctg][p][0] = pd0;
            pdpart[ctg][p][1] = pd1;
        }
    }
    __syncthreads();

    // ---- phase E: final write: out = dpeproj + scattered decoder result ----
    {
        float* outn = out + n * C_IN * POS_PER_SAMPLE;
        for (int i = tid; i < C_IN * POS_PER_SAMPLE; i += THREADS) {
            int o = (i >= POS_PER_SAMPLE) ? 1 : 0;
            int pos = i - o * POS_PER_SAMPLE;
            float v = dpeproj[i];
            int p = rev_sh[pos];
            if (p >= 0)
                v += pdpart[0][p][o] + pdpart[1][p][o]
                   + pdpart[2][p][o] + pdpart[3][p][o];
            outn[i] = v;
        }
    }
}

// ---------------------------------------------------------------------------
extern "C" void kernel_launch(void* const* d_in, const int* in_sizes, int n_in,
                              void* d_out, int out_size, void* d_ws, size_t ws_size,
                              hipStream_t stream) {
    const float* x             = (const float*)d_in[0];
    const float* frame_noise   = (const float*)d_in[1];
    const float* joint_noise   = (const float*)d_in[2];
    const float* pos_embed     = (const float*)d_in[3];
    const float* dec_pos_embed = (const float*)d_in[4];
    const float* w_in          = (const float*)d_in[5];
    const float* b_in          = (const float*)d_in[6];
    const float* w_enc         = (const float*)d_in[7];
    const float* w_dec         = (const float*)d_in[8];
    float* out = (float*)d_out;

    // ws layout: dpeproj (3120 f32) | wbf (16384 bf16) | srcg (256*504 int)
    //            | revg (256*1560 short)
    float* dpeproj = (float*)d_ws;
    __bf16* wbf    = (__bf16*)(dpeproj + C_IN * POS_PER_SAMPLE);
    int*   srcg    = (int*)(wbf + E_DIM * H_DIM);
    short* revg    = (short*)(srcg + N_SAMP * NPOS);

    prep_kernel<<<333, 256, 0, stream>>>(w_dec, dec_pos_embed, w_enc,
                                         frame_noise, joint_noise,
                                         dpeproj, wbf, srcg, revg);

    fused_kernel<<<N_SAMP, THREADS, 0, stream>>>(
        x, pos_embed, w_in, b_in, wbf, w_dec, dpeproj,
        srcg, revg, out);
}